// Round 13
// baseline (356.311 us; speedup 1.0000x reference)
//
#include <hip/hip_runtime.h>

// ConvLSTM2D (B=16,T=5,H=W=256,Cin=3,F=8) + BN + LeakyReLU + Dense(8->2)
// ROUND 13: 5 steps in 3 dispatches (2+2+1). r12 fused-5 is issue-bound
// (VALU 52% + MFMA 25% = 77% SIMD issue) on 1.56x redundant work at 2
// blocks/CU; r9 multi-launch is pinned ~40us/dispatch x 5. Here: tile 28x16,
// region 32x20 -> TWO non-overlapping 16px strips (r12's 3-strips-over-40
// wasted 25% on duplicate columns). Each pair-kernel: h of the intermediate
// step stays in LDS (zero-ring + out-of-image masking, r11-validated);
// h/c ping-pong globally BETWEEN kernels (race-free, r4-validated).
// x staged with its own 1px ring (exact); only h-conv shrinks the cone
// 1px/in-kernel-step -> exact on 30x18 > 28x16 written tile. c fp16 global.

#define BB  16
#define TT  5
#define HH  256
#define WW  256
#define CIN 3
#define FF  8
#define GG  32

#define TWO 28     // output tile width  (grid x = 10, last tile clipped)
#define THO 16     // output tile height
#define RW  32     // region width  = 2 strips, no overlap
#define RH  20     // region height
#define LWW 34     // LDS width  (RW + x-ring)
#define LHH 22     // LDS height (RH + x-ring)
#define NRW 5      // region rows per wave
#define GX  10     // ceil(WW/TWO)

#define LOG2E 1.44269504088896340736f

typedef _Float16 half8  __attribute__((ext_vector_type(8)));
typedef _Float16 half4  __attribute__((ext_vector_type(4)));
typedef float    floatx4 __attribute__((ext_vector_type(4)));

__device__ __forceinline__ float frcp(float x) { return __builtin_amdgcn_rcpf(x); }
__device__ __forceinline__ float sig2(float z)  { return frcp(1.0f + __builtin_amdgcn_exp2f(z)); }
__device__ __forceinline__ float tanh2(float z) { return 1.0f - 2.0f * frcp(1.0f + __builtin_amdgcn_exp2f(z)); }

#define MFMA(A, B, C) __builtin_amdgcn_mfma_f32_16x16x32_f16((A), (B), (C), 0, 0, 0)

// ---------------------------------------------------------------------------
// 16 B-fragments, activation scale folded per column (i,f,o: -log2e; g: +2log2e)
// frag 0..9 = hi (chunks 0..4 x 2 col-halves); 10..15 = lo for h-conv chunks.
// B layout: n = lane&15, k = quad*8+j.
// ---------------------------------------------------------------------------
__global__ void build_frags(const float* __restrict__ wk,
                            const float* __restrict__ wr,
                            _Float16* __restrict__ blob) {
    const int lane = threadIdx.x & 63;
    const int quad = lane >> 4, nlo = lane & 15;
    for (int chunk = 0; chunk < 5; ++chunk) {
        for (int nh = 0; nh < 2; ++nh) {
            const int n = nh * 16 + nlo;
            const float scale = (n >= 16 && n < 24) ? (2.0f * LOG2E) : (-LOG2E);
            const int frag = chunk * 2 + nh;
            _Float16* dhi = blob + ((size_t)frag * 64 + lane) * 8;
            _Float16* dlo = (chunk >= 2)
                ? blob + ((size_t)(10 + (chunk - 2) * 2 + nh) * 64 + lane) * 8
                : nullptr;
            for (int j = 0; j < 8; ++j) {
                const int k = quad * 8 + j;
                float w = 0.0f;
                if (chunk == 0) {
                    int tap = k >> 2, ci = k & 3;
                    if (ci < 3) w = wk[(tap * 3 + ci) * GG + n];
                } else if (chunk == 1) {
                    if (quad == 0 && j < 3) w = wk[(8 * 3 + j) * GG + n];
                } else {
                    int c = chunk - 2;
                    int tap = c * 4 + quad, ci = j;
                    if (tap < 9) w = wr[(tap * FF + ci) * GG + n];
                }
                w *= scale;
                _Float16 wh = (_Float16)w;
                dhi[j] = wh;
                if (dlo) dlo[j] = (_Float16)(w - (float)wh);
            }
        }
    }
}

// ---------------------------------------------------------------------------
// NS timesteps (T0..T0+NS-1) per dispatch. grid (10,16,16) x 256 thr.
// FIRST: no h/c input. LAST: epilogue -> out instead of h/c output.
// ---------------------------------------------------------------------------
template <int T0, int NS, bool FIRST, bool LAST>
__global__ __launch_bounds__(256) void lstm_multi(
    const float* __restrict__ xg,       // [B,T,H,W,3] fp32
    const _Float16* __restrict__ blob,
    const float* __restrict__ bias,
    const _Float16* __restrict__ hin,   // [B,H,W,8] fp16 (h at T0-1)
    _Float16* __restrict__ hout,        // [B,H,W,8] fp16 (h at T0+NS-1)
    const _Float16* __restrict__ cin,   // [B,H,W,8] fp16
    _Float16* __restrict__ cout,        // [B,H,W,8] fp16
    const float* __restrict__ gamma, const float* __restrict__ beta,
    const float* __restrict__ mean,  const float* __restrict__ var,
    const float* __restrict__ dw,    const float* __restrict__ db,
    float* __restrict__ out)
{
    __shared__ half8 hAs[LHH * LWW];   // h ping (11.9 KB)
    __shared__ half8 hBs[LHH * LWW];   // h pong
    __shared__ half4 xls[LHH * LWW];   // x + ring, restaged per sub-step

    const int tid  = threadIdx.x;
    const int bx = blockIdx.x, by = blockIdx.y, b = blockIdx.z;
    const int lane = tid & 63, wave = tid >> 6;
    const int quad = lane >> 4, nlo = lane & 15;
    const bool lo8 = (nlo < 8);
    const int fc = nlo & 7;
    const int m0 = quad * 4 + (lo8 ? 0 : 2);   // strip-local pixel (of 2)

    // lane-constant LDS tap offsets
    const int xt0 = 2 * quad, xt1 = xt0 + 1;
    const int xoff0 = (xt0 / 3) * LWW + (xt0 % 3);
    const int xoff1 = (xt1 / 3) * LWW + (xt1 % 3);
    const int xoff2 = 2 * LWW + 2;
    int hoff[3];
#pragma unroll
    for (int c = 0; c < 3; ++c) {
        int tap = c * 4 + quad;
        if (tap > 8) tap = 8;
        hoff[c] = (tap / 3) * LWW + (tap % 3);
    }

    // B-fragments resident
    half8 bfh[10], bfl[6];
#pragma unroll
    for (int i = 0; i < 10; ++i)
        bfh[i] = *(const half8*)(blob + ((size_t)i * 64 + lane) * 8);
#pragma unroll
    for (int i = 0; i < 6; ++i)
        bfl[i] = *(const half8*)(blob + ((size_t)(10 + i) * 64 + lane) * 8);

    const float bv0 = bias[nlo] * (-LOG2E);
    const float bv1 = bias[16 + nlo] * (lo8 ? 2.0f * LOG2E : -LOG2E);

    float bn_s = 0.f, bn_b = 0.f, dw0 = 0.f, dw1 = 0.f, db0 = 0.f, db1 = 0.f;
    if (LAST) {
        bn_s = gamma[fc] * rsqrtf(var[fc] + 1e-3f);
        bn_b = beta[fc] - mean[fc] * bn_s;
        dw0 = dw[fc * 2 + 0]; dw1 = dw[fc * 2 + 1];
        db0 = db[0]; db1 = db[1];
    }

    // zero both h buffers (ring stays 0; interior overwritten below/each step)
    const half8 hz = {(_Float16)0, (_Float16)0, (_Float16)0, (_Float16)0,
                      (_Float16)0, (_Float16)0, (_Float16)0, (_Float16)0};
    for (int l = tid; l < LHH * LWW; l += 256) { hAs[l] = hz; hBs[l] = hz; }

    // c state in registers (+ preload from global if !FIRST)
    float c0r[NRW][2], c1r[NRW][2];
#pragma unroll
    for (int r = 0; r < NRW; ++r) { c0r[r][0] = c0r[r][1] = 0.f;
                                    c1r[r][0] = c1r[r][1] = 0.f; }
    if (!FIRST) {
#pragma unroll
        for (int r = 0; r < NRW; ++r) {
#pragma unroll
            for (int st = 0; st < 2; ++st) {
                const int row = wave * NRW + r;
                const int iy  = by * THO + row - 2;
                const int ix0 = bx * TWO + st * 16 + m0 - 2;
                if ((unsigned)iy < HH) {
                    const size_t base = ((size_t)(b * HH + iy) * WW) * FF + fc;
                    if ((unsigned)ix0 < WW)
                        c0r[r][st] = (float)cin[base + (size_t)ix0 * FF];
                    if ((unsigned)(ix0 + 1) < WW)
                        c1r[r][st] = (float)cin[base + (size_t)(ix0 + 1) * FF];
                }
            }
        }
        // stage h(T0-1) into hAs INCLUDING ring (true values -> step s=0 exact
        // on the whole region; in-kernel shrink starts at s=1)
        for (int l = tid; l < LHH * LWW; l += 256) {
            int rr = l / LWW, rc = l - rr * LWW;
            int iy = by * THO + rr - 3, ix = bx * TWO + rc - 3;
            half8 v = hz;
            if ((unsigned)iy < HH && (unsigned)ix < WW)
                v = *(const half8*)(hin + ((size_t)(b * HH + iy) * WW + ix) * FF);
            hAs[l] = v;
        }
    }

#pragma unroll
    for (int s = 0; s < NS; ++s) {
        __syncthreads();   // prior compute done (xls/h reads), h/zero staging visible

        // ---- stage x(T0+s) incl. ring (fp32 -> fp16), zero outside image ----
        for (int l = tid; l < LHH * LWW; l += 256) {
            int rr = l / LWW, rc = l - rr * LWW;
            int iy = by * THO + rr - 3, ix = bx * TWO + rc - 3;
            half4 vh = {(_Float16)0, (_Float16)0, (_Float16)0, (_Float16)0};
            if ((unsigned)iy < HH && (unsigned)ix < WW) {
                const float* p = xg + (((size_t)(b * TT + T0 + s) * HH + iy) * WW + ix) * CIN;
                vh.x = (_Float16)p[0]; vh.y = (_Float16)p[1]; vh.z = (_Float16)p[2];
            }
            xls[l] = vh;
        }
        __syncthreads();

        const bool hconv = (s > 0) || !FIRST;
        half8* hRd = (s & 1) ? hBs : hAs;
        half8* hWr = (s & 1) ? hAs : hBs;

#pragma unroll
        for (int r = 0; r < NRW; ++r) {
            const int row = wave * NRW + r;          // region row 0..19
            const int rowbase = row * LWW + nlo;

            // batch LDS loads for both strips
            half4 xp[2], xq[2], xs_[2];
            half8 ah[2][3];
#pragma unroll
            for (int st = 0; st < 2; ++st) {
                const int base = rowbase + st * 16;
                xp[st]  = xls[base + xoff0];
                xq[st]  = xls[base + xoff1];
                xs_[st] = xls[base + xoff2];
                if (hconv) {
#pragma unroll
                    for (int c = 0; c < 3; ++c)
                        ah[st][c] = hRd[base + hoff[c]];
                }
            }

#pragma unroll
            for (int st = 0; st < 2; ++st) {
                const int gx0 = st * 16;             // strip origin (region col)

                half8 a_xA = (half8){xp[st].x, xp[st].y, xp[st].z, xp[st].w,
                                     xq[st].x, xq[st].y, xq[st].z, xq[st].w};
                half8 a_xB = (half8){xs_[st].x, xs_[st].y, xs_[st].z, xs_[st].w,
                                     xs_[st].x, xs_[st].y, xs_[st].z, xs_[st].w};

                floatx4 acc0 = {bv0, bv0, bv0, bv0};
                floatx4 acc1 = {bv1, bv1, bv1, bv1};
                acc0 = MFMA(a_xA, bfh[0], acc0);  acc1 = MFMA(a_xA, bfh[1], acc1);
                acc0 = MFMA(a_xB, bfh[2], acc0);  acc1 = MFMA(a_xB, bfh[3], acc1);
                if (hconv) {
#pragma unroll
                    for (int c = 0; c < 3; ++c) {
                        acc0 = MFMA(ah[st][c], bfh[4 + c * 2], acc0);
                        acc1 = MFMA(ah[st][c], bfh[5 + c * 2], acc1);
                        acc0 = MFMA(ah[st][c], bfl[c * 2 + 0], acc0);
                        acc1 = MFMA(ah[st][c], bfl[c * 2 + 1], acc1);
                    }
                }

                // gate phase (C layout: px m=quad*4+reg, ch=nlo / nlo+16)
                float s0 = lo8 ? acc0[2] : acc0[0]; float r0 = __shfl_xor(s0, 8, 64);
                float s1 = lo8 ? acc0[3] : acc0[1]; float r1 = __shfl_xor(s1, 8, 64);
                float s2 = lo8 ? acc1[2] : acc1[0]; float r2 = __shfl_xor(s2, 8, 64);
                float s3 = lo8 ? acc1[3] : acc1[1]; float r3 = __shfl_xor(s3, 8, 64);

                const float zi0 = lo8 ? acc0[0] : r0, zi1 = lo8 ? acc0[1] : r1;
                const float zf0 = lo8 ? r0 : acc0[2], zf1 = lo8 ? r1 : acc0[3];
                const float zg0 = lo8 ? acc1[0] : r2, zg1 = lo8 ? acc1[1] : r3;
                const float zo0 = lo8 ? r2 : acc1[2], zo1 = lo8 ? r3 : acc1[3];

                const float ii0 = sig2(zi0), ff0 = sig2(zf0), gg0 = tanh2(zg0), oo0 = sig2(zo0);
                const float cn0 = ff0 * c0r[r][st] + ii0 * gg0;
                const float hn0 = oo0 * tanh2(cn0 * (2.0f * LOG2E));
                const float ii1 = sig2(zi1), ff1 = sig2(zf1), gg1 = tanh2(zg1), oo1 = sig2(zo1);
                const float cn1 = ff1 * c1r[r][st] + ii1 * gg1;
                const float hn1 = oo1 * tanh2(cn1 * (2.0f * LOG2E));
                c0r[r][st] = cn0; c1r[r][st] = cn1;

                const int iy  = by * THO + row - 2;          // image row
                const int pc0 = gx0 + m0;                     // region col of px0
                const int ix0 = bx * TWO + pc0 - 2;           // image col of px0

                if (s < NS - 1) {
                    // intermediate h -> LDS; out-of-image pixels write 0
                    const bool iny = (unsigned)iy < HH;
                    const int idx = (row + 1) * LWW + (pc0 + 1);
                    _Float16* hp = (_Float16*)hWr;
                    hp[idx * 8 + fc] =
                        (iny && (unsigned)ix0 < WW) ? (_Float16)hn0 : (_Float16)0;
                    hp[(idx + 1) * 8 + fc] =
                        (iny && (unsigned)(ix0 + 1) < WW) ? (_Float16)hn1 : (_Float16)0;
                } else if (!LAST) {
                    // final h,c -> global, own-tile interior only
                    const bool trow = (row >= 2 && row < 2 + THO);
                    const bool t0ok = trow && pc0 >= 2 && pc0 < 2 + TWO && (unsigned)ix0 < WW;
                    const bool t1ok = trow && pc0 + 1 >= 2 && pc0 + 1 < 2 + TWO &&
                                      (unsigned)(ix0 + 1) < WW;
                    if (t0ok) {
                        const size_t p = ((size_t)(b * HH + iy) * WW + ix0) * FF + fc;
                        hout[p] = (_Float16)hn0; cout[p] = (_Float16)cn0;
                    }
                    if (t1ok) {
                        const size_t p = ((size_t)(b * HH + iy) * WW + ix0 + 1) * FF + fc;
                        hout[p] = (_Float16)hn1; cout[p] = (_Float16)cn1;
                    }
                } else {
                    // fused epilogue: BN -> LeakyReLU(0.3) -> Dense(8->2)
                    float y0 = bn_s * hn0 + bn_b; y0 = (y0 >= 0.f) ? y0 : 0.3f * y0;
                    float y1 = bn_s * hn1 + bn_b; y1 = (y1 >= 0.f) ? y1 : 0.3f * y1;
                    float p00 = y0 * dw0, p01 = y0 * dw1;
                    float p10 = y1 * dw0, p11 = y1 * dw1;
#pragma unroll
                    for (int m = 1; m <= 4; m <<= 1) {
                        p00 += __shfl_xor(p00, m, 64);
                        p01 += __shfl_xor(p01, m, 64);
                        p10 += __shfl_xor(p10, m, 64);
                        p11 += __shfl_xor(p11, m, 64);
                    }
                    const int j = nlo & 7;
                    if (j < 4) {
                        const int rc = pc0 + (j >> 1);
                        const int k  = j & 1;
                        const int ox = bx * TWO + rc - 2;
                        if (rc >= 2 && rc < 2 + TWO && (unsigned)ox < WW &&
                            row >= 2 && row < 2 + THO) {
                            const int oy = by * THO + row - 2;
                            float val = (j == 0 ? p00 : j == 1 ? p01 : j == 2 ? p10 : p11)
                                        + (k ? db1 : db0);
                            out[((size_t)(b * HH + oy) * WW + ox) * 2 + k] = val;
                        }
                    }
                }
            }
        }
    }
}

extern "C" void kernel_launch(void* const* d_in, const int* in_sizes, int n_in,
                              void* d_out, int out_size, void* d_ws, size_t ws_size,
                              hipStream_t stream) {
    const float* x     = (const float*)d_in[0];
    const float* wk    = (const float*)d_in[1];
    const float* wr    = (const float*)d_in[2];
    const float* bias  = (const float*)d_in[3];
    const float* gamma = (const float*)d_in[4];
    const float* beta  = (const float*)d_in[5];
    const float* mean  = (const float*)d_in[6];
    const float* var   = (const float*)d_in[7];
    const float* dw    = (const float*)d_in[8];
    const float* db    = (const float*)d_in[9];
    float* out = (float*)d_out;

    // ws: blob 32KB | hA | hB | cA | cB (each B*H*W*8 fp16 = 16.78 MB)
    const size_t state = (size_t)BB * HH * WW * FF;
    _Float16* blob = (_Float16*)d_ws;
    _Float16* hA = (_Float16*)((char*)d_ws + 32768);
    _Float16* hB = hA + state;
    _Float16* cA = hB + state;
    _Float16* cB = cA + state;

    build_frags<<<1, 64, 0, stream>>>(wk, wr, blob);

    dim3 grid(GX, HH / THO, BB);   // (10,16,16) = 2560 blocks
    dim3 block(256);
    // K1: t{0,1} -> hA,cA   K2: t{2,3} -> hB,cB   K3: t{4} + epilogue -> out
    lstm_multi<0, 2, true,  false><<<grid, block, 0, stream>>>(
        x, blob, bias, hA, hA, cA, cA, gamma, beta, mean, var, dw, db, out);
    lstm_multi<2, 2, false, false><<<grid, block, 0, stream>>>(
        x, blob, bias, hA, hB, cA, cB, gamma, beta, mean, var, dw, db, out);
    lstm_multi<4, 1, false, true ><<<grid, block, 0, stream>>>(
        x, blob, bias, hB, hB, cB, cB, gamma, beta, mean, var, dw, db, out);
}